// Round 1
// baseline (1099.490 us; speedup 1.0000x reference)
//
#include <hip/hip_runtime.h>
#include <cstddef>

#define SEQ     2048
#define BATCH   2
#define DIMSZ   1024
#define HEADS   16
#define HDIM    64
#define E3      3072
#define RESN    512
#define NTAPS   101
#define NFILT   4
#define MROWS   (BATCH * SEQ)   // 4096

// ---------------------------------------------------------------------------
// Kernel 1: filtered prototype table + positional bias table.
// pos_bias depends only on |i-j|  ->  pbias[h][d], h<16, d<2048.
// table[r][f] = sum_t coeffs[f][t] * proto[r-t]  (causal FIR == FFT conv here)
// ---------------------------------------------------------------------------
__global__ __launch_bounds__(256) void pbias_kernel(
    const float* __restrict__ coeffs,   // (4,101)
    const float* __restrict__ Wpos,     // (16,4)
    float* __restrict__ pbias)          // (16,2048)
{
  __shared__ float table[RESN][NFILT];
  __shared__ float wp[HEADS * NFILT];
  const int tid = threadIdx.x;
  if (tid < HEADS * NFILT) wp[tid] = Wpos[tid];
  for (int rf = tid; rf < RESN * NFILT; rf += 256) {
    const int r = rf >> 2, f = rf & 3;
    const int tmax = r < (NTAPS - 1) ? r : (NTAPS - 1);
    float s = 0.f;
    for (int t = 0; t <= tmax; ++t)
      s += coeffs[f * NTAPS + t] * ((float)(r - t) * (1.0f / (float)(RESN - 1)));
    table[r][f] = s;
  }
  __syncthreads();
  for (int hd = tid; hd < HEADS * SEQ; hd += 256) {
    const int h = hd >> 11, d = hd & (SEQ - 1);
    const float rel = (float)d / (float)(SEQ - 1);
    int idx = (int)rintf(rel * (float)(RESN - 1));   // rint: round-half-even, matches jnp.round
    idx = idx < 0 ? 0 : (idx > RESN - 1 ? RESN - 1 : idx);
    float s = 0.f;
#pragma unroll
    for (int f = 0; f < NFILT; ++f) s += table[idx][f] * wp[h * NFILT + f];
    pbias[hd] = s;
  }
}

// ---------------------------------------------------------------------------
// Kernel 2/4: fp32 SGEMM, C[M][N] = A[M][K] * B[N][K]^T  (both row-major, NT).
// 128x128 tile, BK=16, 256 threads, 8x8 micro-tile per thread.
// LDS stored [k][m] (transposed on store) with +4 pad: reads are b128,
// conflict-free / 2-way per analysis.
// ---------------------------------------------------------------------------
__global__ __launch_bounds__(256) void sgemm_nt(
    const float* __restrict__ A, const float* __restrict__ B,
    float* __restrict__ C, int M, int N, int K)
{
  constexpr int BM = 128, BN = 128, BK = 16;
  __shared__ float As[BK][BM + 4];
  __shared__ float Bs[BK][BN + 4];
  const int tid = threadIdx.x;
  const int tx = tid & 15, ty = tid >> 4;
  const int m0 = blockIdx.y * BM, n0 = blockIdx.x * BN;

  const float* Ab = A + (size_t)m0 * K;
  const float* Bb = B + (size_t)n0 * K;

  float acc[8][8];
#pragma unroll
  for (int i = 0; i < 8; ++i)
#pragma unroll
    for (int j = 0; j < 8; ++j) acc[i][j] = 0.f;

  for (int k0 = 0; k0 < K; k0 += BK) {
#pragma unroll
    for (int ld = 0; ld < 2; ++ld) {
      const int flat = tid + ld * 256;         // 0..511
      const int r = flat >> 2;                 // 0..127
      const int c4 = (flat & 3) << 2;          // 0,4,8,12
      const float4 av = *(const float4*)(Ab + (size_t)r * K + k0 + c4);
      const float4 bv = *(const float4*)(Bb + (size_t)r * K + k0 + c4);
      As[c4 + 0][r] = av.x; As[c4 + 1][r] = av.y; As[c4 + 2][r] = av.z; As[c4 + 3][r] = av.w;
      Bs[c4 + 0][r] = bv.x; Bs[c4 + 1][r] = bv.y; Bs[c4 + 2][r] = bv.z; Bs[c4 + 3][r] = bv.w;
    }
    __syncthreads();
#pragma unroll
    for (int k = 0; k < BK; ++k) {
      const float4 a0 = *(const float4*)&As[k][ty * 8];
      const float4 a1 = *(const float4*)&As[k][ty * 8 + 4];
      const float4 b0 = *(const float4*)&Bs[k][tx * 8];
      const float4 b1 = *(const float4*)&Bs[k][tx * 8 + 4];
      const float a[8] = {a0.x, a0.y, a0.z, a0.w, a1.x, a1.y, a1.z, a1.w};
      const float b[8] = {b0.x, b0.y, b0.z, b0.w, b1.x, b1.y, b1.z, b1.w};
#pragma unroll
      for (int i = 0; i < 8; ++i)
#pragma unroll
        for (int j = 0; j < 8; ++j)
          acc[i][j] = fmaf(a[i], b[j], acc[i][j]);
    }
    __syncthreads();
  }

#pragma unroll
  for (int i = 0; i < 8; ++i) {
    float* Cr = C + (size_t)(m0 + ty * 8 + i) * N + n0 + tx * 8;
    *(float4*)(Cr)     = make_float4(acc[i][0], acc[i][1], acc[i][2], acc[i][3]);
    *(float4*)(Cr + 4) = make_float4(acc[i][4], acc[i][5], acc[i][6], acc[i][7]);
  }
}

// ---------------------------------------------------------------------------
// Kernel 3: fused flash-style attention with distance bias.
// Grid: (S/64 q-tiles, B*H). Block 256 = 16x16 threads, thread -> 4x4 of
// the 64x64 logits tile / 64(rows)x64(dims) O tile.
// Q,K in LDS transposed [d][j] (pad 68) -> b128 inner reads; V natural [j][d];
// P staged via LDS (same-wave write->read, DS pipe is in-order per wave).
// ---------------------------------------------------------------------------
__global__ __launch_bounds__(256) void attn_kernel(
    const float* __restrict__ qkv,     // (4096, 3072): [q | k | v]
    const float* __restrict__ pbias,   // (16, 2048)
    float* __restrict__ attnout)       // (4096, 1024)
{
  const int bh = blockIdx.y;
  const int b = bh >> 4, h = bh & 15;
  const int i0 = blockIdx.x * 64;
  const int tid = threadIdx.x;
  const int tx = tid & 15, ty = tid >> 4;

  __shared__ float Qt[64][68];   // [d][i]
  __shared__ float Kt[64][68];   // [d][j]
  __shared__ float Vs[64][68];   // [j][d]
  __shared__ float Ps[64][68];   // [i][j]
  __shared__ float pb[SEQ];      // bias row for this head, indexed by distance

  for (int idx = tid; idx < SEQ; idx += 256) pb[idx] = pbias[h * SEQ + idx];

  {
    const float* Qg = qkv + (size_t)(b * SEQ + i0) * E3 + h * HDIM;
    for (int idx = tid; idx < 1024; idx += 256) {
      const int r = idx >> 4;               // q row in tile
      const int c4 = (idx & 15) << 2;       // dim
      const float4 v = *(const float4*)(Qg + (size_t)r * E3 + c4);
      Qt[c4 + 0][r] = v.x; Qt[c4 + 1][r] = v.y; Qt[c4 + 2][r] = v.z; Qt[c4 + 3][r] = v.w;
    }
  }

  float acc[4][4];
  float mi[4], li[4];
#pragma unroll
  for (int ii = 0; ii < 4; ++ii) {
    mi[ii] = -1e30f; li[ii] = 0.f;
#pragma unroll
    for (int jj = 0; jj < 4; ++jj) acc[ii][jj] = 0.f;
  }
  __syncthreads();

  const float scale = 0.125f;   // 64^-0.5

  for (int j0 = 0; j0 < SEQ; j0 += 64) {
    const float* Kg = qkv + (size_t)(b * SEQ + j0) * E3 + DIMSZ     + h * HDIM;
    const float* Vg = qkv + (size_t)(b * SEQ + j0) * E3 + 2 * DIMSZ + h * HDIM;
    for (int idx = tid; idx < 1024; idx += 256) {
      const int r = idx >> 4;
      const int c4 = (idx & 15) << 2;
      const float4 kv = *(const float4*)(Kg + (size_t)r * E3 + c4);
      Kt[c4 + 0][r] = kv.x; Kt[c4 + 1][r] = kv.y; Kt[c4 + 2][r] = kv.z; Kt[c4 + 3][r] = kv.w;
      *(float4*)&Vs[r][c4] = *(const float4*)(Vg + (size_t)r * E3 + c4);
    }
    __syncthreads();

    // ---- S = Q K^T (64x64 tile, this thread: rows 4ty.., cols 4tx..) ----
    float s[4][4];
#pragma unroll
    for (int ii = 0; ii < 4; ++ii)
#pragma unroll
      for (int jj = 0; jj < 4; ++jj) s[ii][jj] = 0.f;

#pragma unroll 8
    for (int k = 0; k < 64; ++k) {
      const float4 qf = *(const float4*)&Qt[k][ty << 2];
      const float4 kf = *(const float4*)&Kt[k][tx << 2];
      const float qa[4] = {qf.x, qf.y, qf.z, qf.w};
      const float ka[4] = {kf.x, kf.y, kf.z, kf.w};
#pragma unroll
      for (int ii = 0; ii < 4; ++ii)
#pragma unroll
        for (int jj = 0; jj < 4; ++jj)
          s[ii][jj] = fmaf(qa[ii], ka[jj], s[ii][jj]);
    }

    // ---- online softmax (row stats shared across the 16 tx lanes) ----
#pragma unroll
    for (int ii = 0; ii < 4; ++ii) {
      const int i = i0 + (ty << 2) + ii;
      float lg[4];
      float rm = -1e30f;
#pragma unroll
      for (int jj = 0; jj < 4; ++jj) {
        const int j = j0 + (tx << 2) + jj;
        const int d = i > j ? i - j : j - i;
        lg[jj] = fmaf(s[ii][jj], scale, pb[d]);
        rm = fmaxf(rm, lg[jj]);
      }
#pragma unroll
      for (int off = 1; off < 16; off <<= 1)
        rm = fmaxf(rm, __shfl_xor(rm, off));
      const float newm = fmaxf(mi[ii], rm);
      const float fr = __expf(mi[ii] - newm);
      float rs = 0.f;
      float p[4];
#pragma unroll
      for (int jj = 0; jj < 4; ++jj) {
        p[jj] = __expf(lg[jj] - newm);
        rs += p[jj];
      }
#pragma unroll
      for (int off = 1; off < 16; off <<= 1)
        rs += __shfl_xor(rs, off);
      li[ii] = li[ii] * fr + rs;
      mi[ii] = newm;
#pragma unroll
      for (int jj = 0; jj < 4; ++jj) acc[ii][jj] *= fr;
      *(float4*)&Ps[(ty << 2) + ii][tx << 2] = make_float4(p[0], p[1], p[2], p[3]);
    }

    // ---- O += P V  (reads only own-ty rows of Ps: same-wave data) ----
#pragma unroll 4
    for (int j4 = 0; j4 < 64; j4 += 4) {
      float4 pf[4];
#pragma unroll
      for (int ii = 0; ii < 4; ++ii) pf[ii] = *(const float4*)&Ps[(ty << 2) + ii][j4];
      const float pm[4][4] = {
          {pf[0].x, pf[0].y, pf[0].z, pf[0].w},
          {pf[1].x, pf[1].y, pf[1].z, pf[1].w},
          {pf[2].x, pf[2].y, pf[2].z, pf[2].w},
          {pf[3].x, pf[3].y, pf[3].z, pf[3].w}};
#pragma unroll
      for (int q = 0; q < 4; ++q) {
        const float4 vf = *(const float4*)&Vs[j4 + q][tx << 2];
#pragma unroll
        for (int ii = 0; ii < 4; ++ii) {
          acc[ii][0] = fmaf(pm[ii][q], vf.x, acc[ii][0]);
          acc[ii][1] = fmaf(pm[ii][q], vf.y, acc[ii][1]);
          acc[ii][2] = fmaf(pm[ii][q], vf.z, acc[ii][2]);
          acc[ii][3] = fmaf(pm[ii][q], vf.w, acc[ii][3]);
        }
      }
    }
    __syncthreads();
  }

#pragma unroll
  for (int ii = 0; ii < 4; ++ii) {
    const int i = i0 + (ty << 2) + ii;
    const float inv = 1.0f / li[ii];
    *(float4*)(attnout + (size_t)(b * SEQ + i) * DIMSZ + h * HDIM + (tx << 2)) =
        make_float4(acc[ii][0] * inv, acc[ii][1] * inv, acc[ii][2] * inv, acc[ii][3] * inv);
  }
}

// ---------------------------------------------------------------------------
extern "C" void kernel_launch(void* const* d_in, const int* in_sizes, int n_in,
                              void* d_out, int out_size, void* d_ws, size_t ws_size,
                              hipStream_t stream) {
  const float* x      = (const float*)d_in[0];   // (2,2048,1024)
  const float* Wqkv   = (const float*)d_in[1];   // (3072,1024)
  const float* Wout   = (const float*)d_in[2];   // (1024,1024)
  const float* Wpos   = (const float*)d_in[3];   // (16,4)
  const float* coeffs = (const float*)d_in[4];   // (4,101)
  float* out = (float*)d_out;                    // (2,2048,1024)

  float* qkv     = (float*)d_ws;                          // 4096*3072
  float* attnout = qkv + (size_t)MROWS * E3;              // 4096*1024
  float* pbias   = attnout + (size_t)MROWS * DIMSZ;       // 16*2048

  pbias_kernel<<<1, 256, 0, stream>>>(coeffs, Wpos, pbias);

  dim3 g1(E3 / 128, MROWS / 128);
  sgemm_nt<<<g1, 256, 0, stream>>>(x, Wqkv, qkv, MROWS, E3, DIMSZ);

  dim3 g2(SEQ / 64, BATCH * HEADS);
  attn_kernel<<<g2, 256, 0, stream>>>(qkv, pbias, attnout);

  dim3 g3(DIMSZ / 128, MROWS / 128);
  sgemm_nt<<<g3, 256, 0, stream>>>(attnout, Wout, out, MROWS, DIMSZ, DIMSZ);
}

// Round 4
// 557.188 us; speedup vs baseline: 1.9733x; 1.9733x over previous
//
#include <hip/hip_runtime.h>
#include <cstddef>

#define SEQ     2048
#define BATCH   2
#define DIMSZ   1024
#define HEADS   16
#define HDIM    64
#define E3      3072
#define RESN    512
#define NTAPS   101
#define NFILT   4
#define MROWS   (BATCH * SEQ)   // 4096

typedef __attribute__((ext_vector_type(8))) short bf16x8;
typedef __attribute__((ext_vector_type(4))) float f32x4;

__device__ __forceinline__ unsigned short f2bf(float f) {
  unsigned u = __float_as_uint(f);
  u += 0x7fffu + ((u >> 16) & 1u);          // RNE to bf16
  return (unsigned short)(u >> 16);
}
__device__ __forceinline__ float bf2f(unsigned short h) {
  return __uint_as_float(((unsigned)h) << 16);
}
// split f32 -> (hi, lo) bf16 pair: f ~= hi + lo, residual ~2^-17 relative
__device__ __forceinline__ void split2(float f, unsigned short& h, unsigned short& l) {
  h = f2bf(f);
  l = f2bf(f - bf2f(h));
}

// ---------------------------------------------------------------------------
// Kernel 1: positional bias table. pos_bias depends only on |i-j| -> (16,2048)
// ---------------------------------------------------------------------------
__global__ __launch_bounds__(256) void pbias_kernel(
    const float* __restrict__ coeffs, const float* __restrict__ Wpos,
    float* __restrict__ pbias)
{
  __shared__ float table[RESN][NFILT];
  __shared__ float wp[HEADS * NFILT];
  const int tid = threadIdx.x;
  if (tid < HEADS * NFILT) wp[tid] = Wpos[tid];
  for (int rf = tid; rf < RESN * NFILT; rf += 256) {
    const int r = rf >> 2, f = rf & 3;
    const int tmax = r < (NTAPS - 1) ? r : (NTAPS - 1);
    float s = 0.f;
    for (int t = 0; t <= tmax; ++t)
      s += coeffs[f * NTAPS + t] * ((float)(r - t) * (1.0f / (float)(RESN - 1)));
    table[r][f] = s;
  }
  __syncthreads();
  for (int hd = tid; hd < HEADS * SEQ; hd += 256) {
    const int h = hd >> 11, d = hd & (SEQ - 1);
    const float rel = (float)d / (float)(SEQ - 1);
    int idx = (int)rintf(rel * (float)(RESN - 1));
    idx = idx < 0 ? 0 : (idx > RESN - 1 ? RESN - 1 : idx);
    float s = 0.f;
#pragma unroll
    for (int f = 0; f < NFILT; ++f) s += table[idx][f] * wp[h * NFILT + f];
    pbias[hd] = s;
  }
}

// ---------------------------------------------------------------------------
// Kernel 2/4: split-bf16 MFMA GEMM, C[M][N] = A[M][K]*B[N][K]^T (f32 in/out).
// 128x128 tile, BK=32, 256 thr = 4 waves (2x2), each wave 64x64 = 4x4 frags.
// On-the-fly decompose f32 -> bf16 hi/lo during staging; 3 MFMAs per frag.
// LDS pitch 40 ushorts (80 B): 16B-aligned b128 reads, <=2-way conflicts.
// ---------------------------------------------------------------------------
__global__ __launch_bounds__(256) void gemm_split(
    const float* __restrict__ A, const float* __restrict__ B,
    float* __restrict__ C, int M, int N, int K)
{
  constexpr int PIT = 40;
  __shared__ unsigned short AH[128][PIT], AL[128][PIT];
  __shared__ unsigned short BH[128][PIT], BL[128][PIT];
  const int tid = threadIdx.x;
  const int lane = tid & 63;
  const int w = tid >> 6, wm = w >> 1, wn = w & 1;
  const int c = lane & 15, G = lane >> 4;
  const int m0 = blockIdx.y * 128, n0 = blockIdx.x * 128;

  f32x4 acc[4][4];
#pragma unroll
  for (int mf = 0; mf < 4; ++mf)
#pragma unroll
    for (int nf = 0; nf < 4; ++nf) acc[mf][nf] = (f32x4){0.f, 0.f, 0.f, 0.f};

  for (int k0 = 0; k0 < K; k0 += 32) {
    float4 va[4], vb[4];
#pragma unroll
    for (int rep = 0; rep < 4; ++rep) {
      const int u = tid + rep * 256;
      const int row = u >> 3, kq = (u & 7) << 2;
      va[rep] = *(const float4*)(A + (size_t)(m0 + row) * K + k0 + kq);
      vb[rep] = *(const float4*)(B + (size_t)(n0 + row) * K + k0 + kq);
    }
    __syncthreads();   // previous iteration's LDS reads complete
#pragma unroll
    for (int rep = 0; rep < 4; ++rep) {
      const int u = tid + rep * 256;
      const int row = u >> 3, kq = (u & 7) << 2;
      const float fa[4] = {va[rep].x, va[rep].y, va[rep].z, va[rep].w};
      const float fb[4] = {vb[rep].x, vb[rep].y, vb[rep].z, vb[rep].w};
      ushort4 ah, al, bh, bl;
      split2(fa[0], ah.x, al.x); split2(fa[1], ah.y, al.y);
      split2(fa[2], ah.z, al.z); split2(fa[3], ah.w, al.w);
      split2(fb[0], bh.x, bl.x); split2(fb[1], bh.y, bl.y);
      split2(fb[2], bh.z, bl.z); split2(fb[3], bh.w, bl.w);
      *(ushort4*)&AH[row][kq] = ah; *(ushort4*)&AL[row][kq] = al;
      *(ushort4*)&BH[row][kq] = bh; *(ushort4*)&BL[row][kq] = bl;
    }
    __syncthreads();

    bf16x8 fah[4], fal[4];
#pragma unroll
    for (int mf = 0; mf < 4; ++mf) {
      fah[mf] = *(const bf16x8*)&AH[wm * 64 + mf * 16 + c][G * 8];
      fal[mf] = *(const bf16x8*)&AL[wm * 64 + mf * 16 + c][G * 8];
    }
#pragma unroll
    for (int nf = 0; nf < 4; ++nf) {
      const bf16x8 fbh = *(const bf16x8*)&BH[wn * 64 + nf * 16 + c][G * 8];
      const bf16x8 fbl = *(const bf16x8*)&BL[wn * 64 + nf * 16 + c][G * 8];
#pragma unroll
      for (int mf = 0; mf < 4; ++mf) {
        acc[mf][nf] = __builtin_amdgcn_mfma_f32_16x16x32_bf16(fah[mf], fbh, acc[mf][nf], 0, 0, 0);
        acc[mf][nf] = __builtin_amdgcn_mfma_f32_16x16x32_bf16(fah[mf], fbl, acc[mf][nf], 0, 0, 0);
        acc[mf][nf] = __builtin_amdgcn_mfma_f32_16x16x32_bf16(fal[mf], fbh, acc[mf][nf], 0, 0, 0);
      }
    }
  }

#pragma unroll
  for (int mf = 0; mf < 4; ++mf)
#pragma unroll
    for (int nf = 0; nf < 4; ++nf)
#pragma unroll
      for (int r = 0; r < 4; ++r)
        C[(size_t)(m0 + wm * 64 + mf * 16 + 4 * G + r) * N + n0 + wn * 64 + nf * 16 + c] =
            acc[mf][nf][r];
}

// ---------------------------------------------------------------------------
// Kernel 3: MFMA flash attention with distance bias (split-bf16).
// Block: 64 q-rows, 4 waves (16 rows each). Swapped QK^T: S^T = K*Q^T so
// softmax rows are lane-local (i = w*16 + (lane&15)). V transposed in LDS.
// P staged hi/lo through LDS per-wave. Pitch 72 ushorts (144 B): 16B-aligned.
// ---------------------------------------------------------------------------
__global__ __launch_bounds__(256) void attn_mfma(
    const float* __restrict__ qkv,     // (4096,3072) f32
    const float* __restrict__ pbias,   // (16,2048)
    float* __restrict__ attnout)       // (4096,1024) f32
{
  constexpr int PIT = 72;
  __shared__ unsigned short Qh[64][PIT], Ql[64][PIT];
  __shared__ unsigned short Kh[64][PIT], Kl[64][PIT];
  __shared__ unsigned short Vth[64][PIT], Vtl[64][PIT];   // [d][j]
  __shared__ unsigned short Psh[64][PIT], Psl[64][PIT];   // [i][j]
  __shared__ float pb[SEQ];

  const int tid = threadIdx.x;
  const int lane = tid & 63;
  const int w = tid >> 6;
  const int c = lane & 15, G = lane >> 4;
  const int bh = blockIdx.y, b = bh >> 4, h = bh & 15;
  const int i0 = blockIdx.x * 64;
  const int i_glob = i0 + w * 16 + c;
  const float scale = 0.125f;

  for (int idx = tid; idx < SEQ; idx += 256) pb[idx] = pbias[h * SEQ + idx];

  {  // stage Q (hi/lo)
    const float* Qg = qkv + (size_t)(b * SEQ + i0) * E3 + h * HDIM;
#pragma unroll
    for (int rep = 0; rep < 4; ++rep) {
      const int u = tid + rep * 256;
      const int r = u >> 4, dq = (u & 15) << 2;
      const float4 v = *(const float4*)(Qg + (size_t)r * E3 + dq);
      ushort4 hh, ll;
      split2(v.x, hh.x, ll.x); split2(v.y, hh.y, ll.y);
      split2(v.z, hh.z, ll.z); split2(v.w, hh.w, ll.w);
      *(ushort4*)&Qh[r][dq] = hh; *(ushort4*)&Ql[r][dq] = ll;
    }
  }
  __syncthreads();

  // hoist Q B-fragments (k = d = 32*ks + 8*G + e), row i = w*16 + c
  bf16x8 qbh[2], qbl[2];
#pragma unroll
  for (int ks = 0; ks < 2; ++ks) {
    qbh[ks] = *(const bf16x8*)&Qh[w * 16 + c][ks * 32 + G * 8];
    qbl[ks] = *(const bf16x8*)&Ql[w * 16 + c][ks * 32 + G * 8];
  }

  f32x4 oacc[4];
#pragma unroll
  for (int nf = 0; nf < 4; ++nf) oacc[nf] = (f32x4){0.f, 0.f, 0.f, 0.f};
  float mi = -1e30f, li = 0.f;

  for (int jt = 0; jt < SEQ / 64; ++jt) {
    const int j0 = jt * 64;
    const float* Kg = qkv + (size_t)(b * SEQ + j0) * E3 + DIMSZ + h * HDIM;
    const float* Vg = qkv + (size_t)(b * SEQ + j0) * E3 + 2 * DIMSZ + h * HDIM;

    // issue global loads early (overlap with prev tile compute)
    float4 kv[4];
#pragma unroll
    for (int rep = 0; rep < 4; ++rep) {
      const int u = tid + rep * 256;
      const int jr = u >> 4, dq = (u & 15) << 2;
      kv[rep] = *(const float4*)(Kg + (size_t)jr * E3 + dq);
    }
    float4 vv[2][2];
#pragma unroll
    for (int rep = 0; rep < 2; ++rep) {
      const int u = tid + rep * 256;
      const int d4 = (u & 15) << 2, jp = (u >> 4) << 1;
      vv[rep][0] = *(const float4*)(Vg + (size_t)jp * E3 + d4);
      vv[rep][1] = *(const float4*)(Vg + (size_t)(jp + 1) * E3 + d4);
    }
    __syncthreads();   // prev tile done reading K/V LDS

    // K: natural [j][d]
#pragma unroll
    for (int rep = 0; rep < 4; ++rep) {
      const int u = tid + rep * 256;
      const int jr = u >> 4, dq = (u & 15) << 2;
      ushort4 hh, ll;
      split2(kv[rep].x, hh.x, ll.x); split2(kv[rep].y, hh.y, ll.y);
      split2(kv[rep].z, hh.z, ll.z); split2(kv[rep].w, hh.w, ll.w);
      *(ushort4*)&Kh[jr][dq] = hh; *(ushort4*)&Kl[jr][dq] = ll;
    }
    // V: transposed [d][j], packed pairs (j even)
#pragma unroll
    for (int rep = 0; rep < 2; ++rep) {
      const int u = tid + rep * 256;
      const int d4 = (u & 15) << 2, jp = (u >> 4) << 1;
      const float f0[4] = {vv[rep][0].x, vv[rep][0].y, vv[rep][0].z, vv[rep][0].w};
      const float f1[4] = {vv[rep][1].x, vv[rep][1].y, vv[rep][1].z, vv[rep][1].w};
#pragma unroll
      for (int e = 0; e < 4; ++e) {
        unsigned short h0, l0, h1, l1;
        split2(f0[e], h0, l0); split2(f1[e], h1, l1);
        *(unsigned*)&Vth[d4 + e][jp] = (unsigned)h0 | ((unsigned)h1 << 16);
        *(unsigned*)&Vtl[d4 + e][jp] = (unsigned)l0 | ((unsigned)l1 << 16);
      }
    }
    __syncthreads();

    // ---- S^T = K * Q^T : A = K rows (j), B = Q^T, C cols = i (lane-local) --
    f32x4 st[4];
#pragma unroll
    for (int mf = 0; mf < 4; ++mf) st[mf] = (f32x4){0.f, 0.f, 0.f, 0.f};
#pragma unroll
    for (int ks = 0; ks < 2; ++ks) {
#pragma unroll
      for (int mf = 0; mf < 4; ++mf) {
        const bf16x8 kah = *(const bf16x8*)&Kh[mf * 16 + c][ks * 32 + G * 8];
        const bf16x8 kal = *(const bf16x8*)&Kl[mf * 16 + c][ks * 32 + G * 8];
        st[mf] = __builtin_amdgcn_mfma_f32_16x16x32_bf16(kah, qbh[ks], st[mf], 0, 0, 0);
        st[mf] = __builtin_amdgcn_mfma_f32_16x16x32_bf16(kah, qbl[ks], st[mf], 0, 0, 0);
        st[mf] = __builtin_amdgcn_mfma_f32_16x16x32_bf16(kal, qbh[ks], st[mf], 0, 0, 0);
      }
    }

    // ---- online softmax; lane holds 16 logits of q-row i_glob ----
    float p[16];
    float rm = -1e30f;
#pragma unroll
    for (int mf = 0; mf < 4; ++mf)
#pragma unroll
      for (int r = 0; r < 4; ++r) {
        const int j = j0 + 16 * mf + 4 * G + r;
        const int d = i_glob > j ? i_glob - j : j - i_glob;
        const float lg = fmaf(st[mf][r], scale, pb[d]);
        p[mf * 4 + r] = lg;
        rm = fmaxf(rm, lg);
      }
    rm = fmaxf(rm, __shfl_xor(rm, 16));
    rm = fmaxf(rm, __shfl_xor(rm, 32));
    const float newm = fmaxf(mi, rm);
    const float fr = __expf(mi - newm);
    float rs = 0.f;
#pragma unroll
    for (int t = 0; t < 16; ++t) {
      p[t] = __expf(p[t] - newm);
      rs += p[t];
    }
    rs += __shfl_xor(rs, 16);
    rs += __shfl_xor(rs, 32);
    li = li * fr + rs;
    mi = newm;
    // rescale O: O rows are i = w*16 + 4G + r -> fetch fr from lane 20G + r
    float frr[4];
#pragma unroll
    for (int r = 0; r < 4; ++r) frr[r] = __shfl(fr, 20 * G + r);
#pragma unroll
    for (int nf = 0; nf < 4; ++nf)
#pragma unroll
      for (int r = 0; r < 4; ++r) oacc[nf][r] *= frr[r];

    // ---- stage P (hi/lo) into LDS: row i = w*16+c, cols j = 16mf+4G+{0..3}
#pragma unroll
    for (int mf = 0; mf < 4; ++mf) {
      ushort4 ph, pl;
      split2(p[mf * 4 + 0], ph.x, pl.x); split2(p[mf * 4 + 1], ph.y, pl.y);
      split2(p[mf * 4 + 2], ph.z, pl.z); split2(p[mf * 4 + 3], ph.w, pl.w);
      *(ushort4*)&Psh[w * 16 + c][16 * mf + 4 * G] = ph;
      *(ushort4*)&Psl[w * 16 + c][16 * mf + 4 * G] = pl;
    }

    // ---- O += P V : A = P row i, B = V (via V^T LDS) ----
#pragma unroll
    for (int ks = 0; ks < 2; ++ks) {
      const bf16x8 pah = *(const bf16x8*)&Psh[w * 16 + c][ks * 32 + G * 8];
      const bf16x8 pal = *(const bf16x8*)&Psl[w * 16 + c][ks * 32 + G * 8];
#pragma unroll
      for (int nf = 0; nf < 4; ++nf) {
        const bf16x8 vbh = *(const bf16x8*)&Vth[nf * 16 + c][ks * 32 + G * 8];
        const bf16x8 vbl = *(const bf16x8*)&Vtl[nf * 16 + c][ks * 32 + G * 8];
        oacc[nf] = __builtin_amdgcn_mfma_f32_16x16x32_bf16(pah, vbh, oacc[nf], 0, 0, 0);
        oacc[nf] = __builtin_amdgcn_mfma_f32_16x16x32_bf16(pah, vbl, oacc[nf], 0, 0, 0);
        oacc[nf] = __builtin_amdgcn_mfma_f32_16x16x32_bf16(pal, vbh, oacc[nf], 0, 0, 0);
      }
    }
  }

  // epilogue: normalize rows (stats live on lane 20G + r) and store f32
  float rinv[4];
#pragma unroll
  for (int r = 0; r < 4; ++r) rinv[r] = 1.0f / __shfl(li, 20 * G + r);
#pragma unroll
  for (int nf = 0; nf < 4; ++nf)
#pragma unroll
    for (int r = 0; r < 4; ++r)
      attnout[(size_t)(b * SEQ + i0 + w * 16 + 4 * G + r) * DIMSZ + h * HDIM + nf * 16 + c] =
          oacc[nf][r] * rinv[r];
}

// ---------------------------------------------------------------------------
extern "C" void kernel_launch(void* const* d_in, const int* in_sizes, int n_in,
                              void* d_out, int out_size, void* d_ws, size_t ws_size,
                              hipStream_t stream) {
  const float* x      = (const float*)d_in[0];
  const float* Wqkv   = (const float*)d_in[1];
  const float* Wout   = (const float*)d_in[2];
  const float* Wpos   = (const float*)d_in[3];
  const float* coeffs = (const float*)d_in[4];
  float* out = (float*)d_out;

  float* qkv     = (float*)d_ws;                       // 4096*3072 f32
  float* attnout = qkv + (size_t)MROWS * E3;           // 4096*1024 f32
  float* pbias   = attnout + (size_t)MROWS * DIMSZ;    // 16*2048 f32

  pbias_kernel<<<1, 256, 0, stream>>>(coeffs, Wpos, pbias);

  dim3 g1(E3 / 128, MROWS / 128);
  gemm_split<<<g1, 256, 0, stream>>>(x, Wqkv, qkv, MROWS, E3, DIMSZ);

  dim3 g2(SEQ / 64, BATCH * HEADS);
  attn_mfma<<<g2, 256, 0, stream>>>(qkv, pbias, attnout);

  dim3 g3(DIMSZ / 128, MROWS / 128);
  gemm_split<<<g3, 256, 0, stream>>>(attnout, Wout, out, MROWS, DIMSZ, DIMSZ);
}

// Round 5
// 332.890 us; speedup vs baseline: 3.3029x; 1.6738x over previous
//
#include <hip/hip_runtime.h>
#include <cstddef>

#define SEQ     2048
#define BATCH   2
#define DIMSZ   1024
#define HEADS   16
#define HDIM    64
#define E3      3072
#define RESN    512
#define NTAPS   101
#define NFILT   4
#define MROWS   (BATCH * SEQ)   // 4096

typedef __attribute__((ext_vector_type(8))) short bf16x8;
typedef __attribute__((ext_vector_type(4))) float f32x4;

__device__ __forceinline__ unsigned short f2bf(float f) {
  unsigned u = __float_as_uint(f);
  u += 0x7fffu + ((u >> 16) & 1u);          // RNE to bf16
  return (unsigned short)(u >> 16);
}
__device__ __forceinline__ float bf2f(unsigned short h) {
  return __uint_as_float(((unsigned)h) << 16);
}
__device__ __forceinline__ void split2(float f, unsigned short& h, unsigned short& l) {
  h = f2bf(f);
  l = f2bf(f - bf2f(h));
}

// ---------------------------------------------------------------------------
// f32 -> bf16 (RNE) bulk convert. n multiple of 8.
// ---------------------------------------------------------------------------
__global__ __launch_bounds__(256) void cvt_bf16_kern(
    const float* __restrict__ src, unsigned short* __restrict__ dst, int n)
{
  const int i = (blockIdx.x * 256 + threadIdx.x) * 8;
  if (i >= n) return;
  const float4 a = *(const float4*)(src + i);
  const float4 b = *(const float4*)(src + i + 4);
  ushort4 p = {f2bf(a.x), f2bf(a.y), f2bf(a.z), f2bf(a.w)};
  ushort4 q = {f2bf(b.x), f2bf(b.y), f2bf(b.z), f2bf(b.w)};
  *(ushort4*)(dst + i)     = p;
  *(ushort4*)(dst + i + 4) = q;
}

// f32 -> (hi, lo) bf16 pair. n multiple of 4.
__global__ __launch_bounds__(256) void split_pair_kern(
    const float* __restrict__ src, unsigned short* __restrict__ hi,
    unsigned short* __restrict__ lo, int n)
{
  const int i = (blockIdx.x * 256 + threadIdx.x) * 4;
  if (i >= n) return;
  const float4 a = *(const float4*)(src + i);
  ushort4 h, l;
  split2(a.x, h.x, l.x); split2(a.y, h.y, l.y);
  split2(a.z, h.z, l.z); split2(a.w, h.w, l.w);
  *(ushort4*)(hi + i) = h;
  *(ushort4*)(lo + i) = l;
}

// ---------------------------------------------------------------------------
// positional bias table: pos_bias depends only on |i-j| -> (16,2048) f32
// ---------------------------------------------------------------------------
__global__ __launch_bounds__(256) void pbias_kernel(
    const float* __restrict__ coeffs, const float* __restrict__ Wpos,
    float* __restrict__ pbias)
{
  __shared__ float table[RESN][NFILT];
  __shared__ float wp[HEADS * NFILT];
  const int tid = threadIdx.x;
  if (tid < HEADS * NFILT) wp[tid] = Wpos[tid];
  for (int rf = tid; rf < RESN * NFILT; rf += 256) {
    const int r = rf >> 2, f = rf & 3;
    const int tmax = r < (NTAPS - 1) ? r : (NTAPS - 1);
    float s = 0.f;
    for (int t = 0; t <= tmax; ++t)
      s += coeffs[f * NTAPS + t] * ((float)(r - t) * (1.0f / (float)(RESN - 1)));
    table[r][f] = s;
  }
  __syncthreads();
  for (int hd = tid; hd < HEADS * SEQ; hd += 256) {
    const int h = hd >> 11, d = hd & (SEQ - 1);
    const float rel = (float)d / (float)(SEQ - 1);
    int idx = (int)rintf(rel * (float)(RESN - 1));
    idx = idx < 0 ? 0 : (idx > RESN - 1 ? RESN - 1 : idx);
    float s = 0.f;
#pragma unroll
    for (int f = 0; f < NFILT; ++f) s += table[idx][f] * wp[h * NFILT + f];
    pbias[hd] = s;
  }
}

// ---------------------------------------------------------------------------
// Pure-bf16 MFMA GEMM: C[m][n] = sum_k A[m][k]*B[n][k], bf16 in, bf16 out.
// 128x128 tile, BK=64, 4 waves 2x2, 4x4 16x16 frags/wave, f32 accum.
// ---------------------------------------------------------------------------
__global__ __launch_bounds__(256) void gemm_bf16(
    const unsigned short* __restrict__ A, const unsigned short* __restrict__ B,
    unsigned short* __restrict__ C, int M, int N, int K)
{
  __shared__ unsigned short As[128][72];
  __shared__ unsigned short Bs[128][72];
  const int tid = threadIdx.x;
  const int lane = tid & 63;
  const int w = tid >> 6, wm = w >> 1, wn = w & 1;
  const int c = lane & 15, G = lane >> 4;
  const int m0 = blockIdx.y * 128, n0 = blockIdx.x * 128;

  f32x4 acc[4][4];
#pragma unroll
  for (int mf = 0; mf < 4; ++mf)
#pragma unroll
    for (int nf = 0; nf < 4; ++nf) acc[mf][nf] = (f32x4){0.f, 0.f, 0.f, 0.f};

  for (int k0 = 0; k0 < K; k0 += 64) {
    bf16x8 va[4], vb[4];
#pragma unroll
    for (int rep = 0; rep < 4; ++rep) {
      const int u = tid + rep * 256;           // 0..1023
      const int row = u >> 3, s = u & 7;
      va[rep] = *(const bf16x8*)(A + (size_t)(m0 + row) * K + k0 + 8 * s);
      vb[rep] = *(const bf16x8*)(B + (size_t)(n0 + row) * K + k0 + 8 * s);
    }
    __syncthreads();
#pragma unroll
    for (int rep = 0; rep < 4; ++rep) {
      const int u = tid + rep * 256;
      const int row = u >> 3, s = u & 7;
      *(bf16x8*)&As[row][8 * s] = va[rep];
      *(bf16x8*)&Bs[row][8 * s] = vb[rep];
    }
    __syncthreads();
#pragma unroll
    for (int ks = 0; ks < 2; ++ks) {
      bf16x8 fa[4], fb[4];
#pragma unroll
      for (int mf = 0; mf < 4; ++mf)
        fa[mf] = *(const bf16x8*)&As[wm * 64 + 16 * mf + c][32 * ks + 8 * G];
#pragma unroll
      for (int nf = 0; nf < 4; ++nf)
        fb[nf] = *(const bf16x8*)&Bs[wn * 64 + 16 * nf + c][32 * ks + 8 * G];
#pragma unroll
      for (int nf = 0; nf < 4; ++nf)
#pragma unroll
        for (int mf = 0; mf < 4; ++mf)
          acc[mf][nf] = __builtin_amdgcn_mfma_f32_16x16x32_bf16(fa[mf], fb[nf], acc[mf][nf], 0, 0, 0);
    }
  }

#pragma unroll
  for (int mf = 0; mf < 4; ++mf)
#pragma unroll
    for (int nf = 0; nf < 4; ++nf)
#pragma unroll
      for (int r = 0; r < 4; ++r)
        C[(size_t)(m0 + wm * 64 + 16 * mf + 4 * G + r) * N + n0 + wn * 64 + 16 * nf + c] =
            f2bf(acc[mf][nf][r]);
}

// ---------------------------------------------------------------------------
// Split-bf16 (3-term) GEMM for the final projection: A as (hi,lo) bf16 pair,
// B as (hi,lo) pair, C f32. 128x128 tile, BK=32.
// ---------------------------------------------------------------------------
__global__ __launch_bounds__(256) void gemm_split3(
    const unsigned short* __restrict__ Ah, const unsigned short* __restrict__ Al,
    const unsigned short* __restrict__ Bh, const unsigned short* __restrict__ Bl,
    float* __restrict__ C, int M, int N, int K)
{
  __shared__ unsigned short AhS[128][40], AlS[128][40];
  __shared__ unsigned short BhS[128][40], BlS[128][40];
  const int tid = threadIdx.x;
  const int lane = tid & 63;
  const int w = tid >> 6, wm = w >> 1, wn = w & 1;
  const int c = lane & 15, G = lane >> 4;
  const int m0 = blockIdx.y * 128, n0 = blockIdx.x * 128;

  f32x4 acc[4][4];
#pragma unroll
  for (int mf = 0; mf < 4; ++mf)
#pragma unroll
    for (int nf = 0; nf < 4; ++nf) acc[mf][nf] = (f32x4){0.f, 0.f, 0.f, 0.f};

  for (int k0 = 0; k0 < K; k0 += 32) {
    bf16x8 vah[2], val[2], vbh[2], vbl[2];
#pragma unroll
    for (int rep = 0; rep < 2; ++rep) {
      const int u = tid + rep * 256;           // 0..511
      const int row = u >> 2, s = u & 3;
      const size_t oa = (size_t)(m0 + row) * K + k0 + 8 * s;
      const size_t ob = (size_t)(n0 + row) * K + k0 + 8 * s;
      vah[rep] = *(const bf16x8*)(Ah + oa);
      val[rep] = *(const bf16x8*)(Al + oa);
      vbh[rep] = *(const bf16x8*)(Bh + ob);
      vbl[rep] = *(const bf16x8*)(Bl + ob);
    }
    __syncthreads();
#pragma unroll
    for (int rep = 0; rep < 2; ++rep) {
      const int u = tid + rep * 256;
      const int row = u >> 2, s = u & 3;
      *(bf16x8*)&AhS[row][8 * s] = vah[rep];
      *(bf16x8*)&AlS[row][8 * s] = val[rep];
      *(bf16x8*)&BhS[row][8 * s] = vbh[rep];
      *(bf16x8*)&BlS[row][8 * s] = vbl[rep];
    }
    __syncthreads();
    bf16x8 fah[4], fal[4];
#pragma unroll
    for (int mf = 0; mf < 4; ++mf) {
      fah[mf] = *(const bf16x8*)&AhS[wm * 64 + 16 * mf + c][8 * G];
      fal[mf] = *(const bf16x8*)&AlS[wm * 64 + 16 * mf + c][8 * G];
    }
#pragma unroll
    for (int nf = 0; nf < 4; ++nf) {
      const bf16x8 fbh = *(const bf16x8*)&BhS[wn * 64 + 16 * nf + c][8 * G];
      const bf16x8 fbl = *(const bf16x8*)&BlS[wn * 64 + 16 * nf + c][8 * G];
#pragma unroll
      for (int mf = 0; mf < 4; ++mf) {
        acc[mf][nf] = __builtin_amdgcn_mfma_f32_16x16x32_bf16(fah[mf], fbh, acc[mf][nf], 0, 0, 0);
        acc[mf][nf] = __builtin_amdgcn_mfma_f32_16x16x32_bf16(fah[mf], fbl, acc[mf][nf], 0, 0, 0);
        acc[mf][nf] = __builtin_amdgcn_mfma_f32_16x16x32_bf16(fal[mf], fbh, acc[mf][nf], 0, 0, 0);
      }
    }
  }

#pragma unroll
  for (int mf = 0; mf < 4; ++mf)
#pragma unroll
    for (int nf = 0; nf < 4; ++nf)
#pragma unroll
      for (int r = 0; r < 4; ++r)
        C[(size_t)(m0 + wm * 64 + 16 * mf + 4 * G + r) * N + n0 + wn * 64 + 16 * nf + c] =
            acc[mf][nf][r];
}

// ---------------------------------------------------------------------------
// Pure-bf16 MFMA flash attention with distance bias.
// qkv: bf16 (4096,3072). Swapped QK^T (S^T = K*Q^T, softmax rows lane-local).
// Q fragments loaded per-lane direct from global (no Q LDS).
// V^T in LDS pitch 64 + 16B-slot XOR swizzle (slot ^= (d>>2)&7): write-free.
// P (hi only) through LDS, same-wave write->read. Output: bf16 hi/lo pair.
// LDS: 9.2K (K) + 8K (V) + 9.2K (P) + 8K (pb) = 34.8 KB -> 4 blocks/CU.
// ---------------------------------------------------------------------------
__global__ __launch_bounds__(256) void attn_pure(
    const unsigned short* __restrict__ qkv,   // bf16 (4096,3072)
    const float* __restrict__ pbias,          // (16,2048) f32
    unsigned short* __restrict__ ao_hi,       // bf16 (4096,1024)
    unsigned short* __restrict__ ao_lo)
{
  __shared__ unsigned short Kh[64][72];
  __shared__ unsigned short Vh[64][64];   // swizzled V^T [d][j]
  __shared__ unsigned short Ps[64][72];
  __shared__ float pb[SEQ];

  const int tid = threadIdx.x;
  const int lane = tid & 63;
  const int w = tid >> 6;
  const int c = lane & 15, G = lane >> 4;
  const int bh = blockIdx.y, b = bh >> 4, h = bh & 15;
  const int i0 = blockIdx.x * 64;
  const int i_glob = i0 + w * 16 + c;
  const float scale = 0.125f;

  for (int idx = tid * 4; idx < SEQ; idx += 1024)
    *(float4*)&pb[idx] = *(const float4*)(pbias + h * SEQ + idx);

  // Q B-fragments direct from global: lane (c,G) row i_glob, d = 32ks+8G+e
  bf16x8 qb[2];
#pragma unroll
  for (int ks = 0; ks < 2; ++ks)
    qb[ks] = *(const bf16x8*)(qkv + (size_t)(b * SEQ + i_glob) * E3 + h * HDIM + 32 * ks + 8 * G);

  f32x4 oacc[4];
#pragma unroll
  for (int nf = 0; nf < 4; ++nf) oacc[nf] = (f32x4){0.f, 0.f, 0.f, 0.f};
  float mi = -1e30f, li = 0.f;

  const int vd8 = 8 * (tid & 7);        // V-stage: this thread's d-block
  const int vjp = 2 * (tid >> 3);       // and j-pair (0..62)

  for (int jt = 0; jt < SEQ / 64; ++jt) {
    const int j0 = jt * 64;
    const size_t rowK = (size_t)(b * SEQ + j0) * E3 + DIMSZ + h * HDIM;
    const size_t rowV = (size_t)(b * SEQ + j0) * E3 + 2 * DIMSZ + h * HDIM;

    // issue global loads early
    bf16x8 kv[2];
#pragma unroll
    for (int rep = 0; rep < 2; ++rep) {
      const int u = tid + rep * 256;         // 0..511
      const int j = u >> 3, s = u & 7;
      kv[rep] = *(const bf16x8*)(qkv + rowK + (size_t)j * E3 + 8 * s);
    }
    const bf16x8 v0 = *(const bf16x8*)(qkv + rowV + (size_t)vjp * E3 + vd8);
    const bf16x8 v1 = *(const bf16x8*)(qkv + rowV + (size_t)(vjp + 1) * E3 + vd8);

    __syncthreads();   // previous tile's LDS reads complete

#pragma unroll
    for (int rep = 0; rep < 2; ++rep) {
      const int u = tid + rep * 256;
      const int j = u >> 3, s = u & 7;
      *(bf16x8*)&Kh[j][8 * s] = kv[rep];
    }
#pragma unroll
    for (int e = 0; e < 8; ++e) {
      const int d = vd8 + e;
      const unsigned pk = (unsigned)(unsigned short)v0[e] |
                          ((unsigned)(unsigned short)v1[e] << 16);
      const int colp = ((((vjp >> 3) ^ ((d >> 2) & 7)) << 3) | (vjp & 7));
      *(unsigned*)&Vh[d][colp] = pk;
    }
    __syncthreads();

    // ---- S^T = K * Q^T ----
    f32x4 st[4];
#pragma unroll
    for (int mf = 0; mf < 4; ++mf) st[mf] = (f32x4){0.f, 0.f, 0.f, 0.f};
#pragma unroll
    for (int ks = 0; ks < 2; ++ks)
#pragma unroll
      for (int mf = 0; mf < 4; ++mf) {
        const bf16x8 ka = *(const bf16x8*)&Kh[16 * mf + c][32 * ks + 8 * G];
        st[mf] = __builtin_amdgcn_mfma_f32_16x16x32_bf16(ka, qb[ks], st[mf], 0, 0, 0);
      }

    // ---- online softmax: lane holds 16 logits of q-row i_glob ----
    float p[16];
    float rm = -1e30f;
#pragma unroll
    for (int mf = 0; mf < 4; ++mf)
#pragma unroll
      for (int r = 0; r < 4; ++r) {
        const int j = j0 + 16 * mf + 4 * G + r;
        const int d = i_glob > j ? i_glob - j : j - i_glob;
        const float lg = fmaf(st[mf][r], scale, pb[d]);
        p[mf * 4 + r] = lg;
        rm = fmaxf(rm, lg);
      }
    rm = fmaxf(rm, __shfl_xor(rm, 16));
    rm = fmaxf(rm, __shfl_xor(rm, 32));
    const float newm = fmaxf(mi, rm);
    const float fr = __expf(mi - newm);
    float rs = 0.f;
#pragma unroll
    for (int t = 0; t < 16; ++t) {
      p[t] = __expf(p[t] - newm);
      rs += p[t];
    }
    rs += __shfl_xor(rs, 16);
    rs += __shfl_xor(rs, 32);
    li = li * fr + rs;
    mi = newm;
    float frr[4];
#pragma unroll
    for (int r = 0; r < 4; ++r) frr[r] = __shfl(fr, 20 * G + r);
#pragma unroll
    for (int nf = 0; nf < 4; ++nf)
#pragma unroll
      for (int r = 0; r < 4; ++r) oacc[nf][r] *= frr[r];

    // ---- stage P (bf16, hi only): row i = 16w+c, cols 16mf+4G+0..3 ----
#pragma unroll
    for (int mf = 0; mf < 4; ++mf) {
      ushort4 ph = {f2bf(p[mf * 4 + 0]), f2bf(p[mf * 4 + 1]),
                    f2bf(p[mf * 4 + 2]), f2bf(p[mf * 4 + 3])};
      *(ushort4*)&Ps[16 * w + c][16 * mf + 4 * G] = ph;
    }

    // ---- O += P V  (same-wave P read; V via swizzled V^T) ----
#pragma unroll
    for (int ks = 0; ks < 2; ++ks) {
      const bf16x8 pa = *(const bf16x8*)&Ps[16 * w + c][32 * ks + 8 * G];
#pragma unroll
      for (int nf = 0; nf < 4; ++nf) {
        const int d = 16 * nf + c;
        const int sl = ((4 * ks + G) ^ ((d >> 2) & 7)) << 3;
        const bf16x8 vb = *(const bf16x8*)&Vh[d][sl];
        oacc[nf] = __builtin_amdgcn_mfma_f32_16x16x32_bf16(pa, vb, oacc[nf], 0, 0, 0);
      }
    }
  }

  // epilogue: normalize (stats on lane 20G+r), write bf16 hi/lo pair
  float rinv[4];
#pragma unroll
  for (int r = 0; r < 4; ++r) rinv[r] = 1.0f / __shfl(li, 20 * G + r);
#pragma unroll
  for (int nf = 0; nf < 4; ++nf)
#pragma unroll
    for (int r = 0; r < 4; ++r) {
      const float v = oacc[nf][r] * rinv[r];
      const size_t off = (size_t)(b * SEQ + i0 + 16 * w + 4 * G + r) * DIMSZ +
                         h * HDIM + 16 * nf + c;
      unsigned short vh, vl;
      split2(v, vh, vl);
      ao_hi[off] = vh;
      ao_lo[off] = vl;
    }
}

// ---------------------------------------------------------------------------
extern "C" void kernel_launch(void* const* d_in, const int* in_sizes, int n_in,
                              void* d_out, int out_size, void* d_ws, size_t ws_size,
                              hipStream_t stream) {
  const float* x      = (const float*)d_in[0];   // (2,2048,1024)
  const float* Wqkv   = (const float*)d_in[1];   // (3072,1024)
  const float* Wout   = (const float*)d_in[2];   // (1024,1024)
  const float* Wpos   = (const float*)d_in[3];   // (16,4)
  const float* coeffs = (const float*)d_in[4];   // (4,101)
  float* out = (float*)d_out;                    // (2,2048,1024)

  // workspace layout (bf16 = ushort), total ~60.9 MB
  unsigned short* qkv_bf  = (unsigned short*)d_ws;           // 4096*3072
  unsigned short* x_bf    = qkv_bf + (size_t)MROWS * E3;     // 4096*1024
  unsigned short* wqkv_bf = x_bf + (size_t)MROWS * DIMSZ;    // 3072*1024
  unsigned short* wout_h  = wqkv_bf + (size_t)E3 * DIMSZ;    // 1024*1024
  unsigned short* wout_l  = wout_h + (size_t)DIMSZ * DIMSZ;
  unsigned short* ao_h    = wout_l + (size_t)DIMSZ * DIMSZ;  // 4096*1024
  unsigned short* ao_l    = ao_h + (size_t)MROWS * DIMSZ;
  float* pbias = (float*)(ao_l + (size_t)MROWS * DIMSZ);     // 16*2048

  const int nx = MROWS * DIMSZ;       // 4194304
  const int nw = E3 * DIMSZ;          // 3145728
  const int no = DIMSZ * DIMSZ;       // 1048576

  cvt_bf16_kern<<<nx / 2048, 256, 0, stream>>>(x, x_bf, nx);
  cvt_bf16_kern<<<nw / 2048, 256, 0, stream>>>(Wqkv, wqkv_bf, nw);
  split_pair_kern<<<no / 1024, 256, 0, stream>>>(Wout, wout_h, wout_l, no);
  pbias_kernel<<<1, 256, 0, stream>>>(coeffs, Wpos, pbias);

  dim3 g1(E3 / 128, MROWS / 128);
  gemm_bf16<<<g1, 256, 0, stream>>>(x_bf, wqkv_bf, qkv_bf, MROWS, E3, DIMSZ);

  dim3 g2(SEQ / 64, BATCH * HEADS);
  attn_pure<<<g2, 256, 0, stream>>>(qkv_bf, pbias, ao_h, ao_l);

  dim3 g3(DIMSZ / 128, MROWS / 128);
  gemm_split3<<<g3, 256, 0, stream>>>(ao_h, ao_l, wout_h, wout_l, out, MROWS, DIMSZ, DIMSZ);
}